// Round 13
// baseline (100.794 us; speedup 1.0000x reference)
//
#include <hip/hip_runtime.h>

typedef _Float16 f16x8 __attribute__((ext_vector_type(8)));
typedef float f32x4 __attribute__((ext_vector_type(4)));

#define MDIM 64000
#define KDIM 512
#define NCOLS 514
#define NPAD 512
#define BM 128
#define BN 128
#define BK 64
#define KT (KDIM / BK)  // 8
#define NT 4            // N tiles (cols 0..511); Nyquist cols 512/513 analytic
#define NWG 2000        // 500 M-tiles x 4 N-tiles, divisible by 8

// global -> LDS direct DMA, 16B per lane, LDS dest = wave-uniform base + lane*16
#define GLOAD_LDS16(g, l)                                        \
  __builtin_amdgcn_global_load_lds(                              \
      (const __attribute__((address_space(1))) void*)(g),        \
      (__attribute__((address_space(3))) void*)(l), 16, 0, 0)

// Build interleaved f16 weight matrix Wb[n][k], n in [0,512):
//   n even -> real_kernel[n/2], n odd -> imag_kernel[n/2]
__global__ void prep_w(const float* __restrict__ rk, const float* __restrict__ ik,
                       _Float16* __restrict__ wb) {
  int n = blockIdx.x;
  int k = threadIdx.x;
  int bin = n >> 1;
  const float* src = (n & 1) ? ik : rk;
  wb[(size_t)n * KDIM + k] = (_Float16)src[bin * KDIM + k];
}

// (256,3): VGPR cap ~168 >= natural ~130 -> no spill (r10 lesson).
__global__ __launch_bounds__(256, 3)
void dft_gemm(const float* __restrict__ x, const _Float16* __restrict__ wb,
              float* __restrict__ out) {
  // r9's serial 2-barrier loop, but A stored f16 (reg-staged, r5's macros):
  // halves LDS write+read traffic (the measured ceiling) and hides A-load
  // latency under COMPUTE. B staged via global_load_lds (r9 verbatim).
  // Chunk swizzle both operands: logical 16B chunk c of row r at phys c^(r&7).
  __shared__ _Float16 As[BM * BK];   // 16 KB
  __shared__ _Float16 Bs[BN * BK];   // 16 KB -> 32 KB total

  const int tid = threadIdx.x;
  const int l   = tid & 63;
  const int w   = tid >> 6;
  const int lr  = l & 15;   // fragment row/col lane index
  const int lg  = l >> 4;   // lane k-group 0..3
  const int wm  = (w >> 1) * 64;
  const int wn  = (w & 1) * 64;

  // T1: XCD swizzle (NWG%8==0 -> chunked bijection). Consecutive wgid -> same
  // XCD, so the 4 N-tile blocks of one M-tile share the x slab in one L2.
  const int wgid = (blockIdx.x & 7) * (NWG / 8) + (blockIdx.x >> 3);
  const int mt = wgid >> 2;
  const int nt = wgid & 3;
  const int m0 = mt * BM;
  const int n0 = nt * BN;

  f32x4 acc[4][4] = {};
  float nyq = 0.0f;

  // A staging (r5 verbatim): thread owns row arow=tid>>1, f32 cols acol..+31
  const int arow = tid >> 1;
  const int acol = (tid & 1) * 32;
  const float* aptr = x + (size_t)(m0 + arow) * KDIM + acol;

  // B staging (r9 verbatim): lane row-in-issue l>>3, phys chunk l&7
  const int brl = l >> 3;
  const int bcp = l & 7;

  f32x4 areg[8];  // in-flight A slice (32 f32), statically indexed

#define ISSUE_A(t)                                                        \
  {                                                                       \
    _Pragma("unroll")                                                     \
    for (int j = 0; j < 8; ++j)                                           \
      areg[j] = *reinterpret_cast<const f32x4*>(aptr + (t) * BK + j * 4); \
  }

#define WRITE_A()                                                         \
  {                                                                       \
    _Pragma("unroll")                                                     \
    for (int c = 0; c < 4; ++c) {                                         \
      f16x8 h;                                                            \
      _Pragma("unroll")                                                   \
      for (int e = 0; e < 4; ++e) {                                       \
        h[e]     = (_Float16)areg[c * 2][e];                              \
        h[e + 4] = (_Float16)areg[c * 2 + 1][e];                          \
      }                                                                   \
      int pc = ((tid & 1) * 4 + c) ^ (arow & 7);                          \
      *reinterpret_cast<f16x8*>(&As[arow * BK + pc * 8]) = h;             \
    }                                                                     \
  }

// Nyquist alternating sum on the f32 regs (r5 verbatim): col base even
#define NYQ()                                                             \
  {                                                                       \
    _Pragma("unroll")                                                     \
    for (int j = 0; j < 8; ++j)                                           \
      nyq += (areg[j][0] - areg[j][1]) + (areg[j][2] - areg[j][3]);       \
  }

#define STAGE_B(t)                                                        \
  {                                                                       \
    _Pragma("unroll")                                                     \
    for (int s = 0; s < 4; ++s) {                                         \
      int r0  = w * 32 + s * 8;                                           \
      int row = r0 + brl;                                                 \
      int cl  = bcp ^ (row & 7);                                          \
      const _Float16* g =                                                 \
          wb + (size_t)(n0 + row) * KDIM + (t) * BK + cl * 8;             \
      GLOAD_LDS16(g, &Bs[r0 * BK]);                                       \
    }                                                                     \
  }

#define COMPUTE()                                                         \
  {                                                                       \
    _Pragma("unroll")                                                     \
    for (int ks = 0; ks < 2; ++ks) {                                      \
      f16x8 av[4], bv[4];                                                 \
      _Pragma("unroll")                                                   \
      for (int fm = 0; fm < 4; ++fm) {                                    \
        int row = wm + fm * 16 + lr;                                      \
        int c   = (ks * 4 + lg) ^ (row & 7);                              \
        av[fm] = *reinterpret_cast<const f16x8*>(&As[row * BK + c * 8]);  \
      }                                                                   \
      _Pragma("unroll")                                                   \
      for (int fn = 0; fn < 4; ++fn) {                                    \
        int row = wn + fn * 16 + lr;                                      \
        int c   = (ks * 4 + lg) ^ (row & 7);                              \
        bv[fn] = *reinterpret_cast<const f16x8*>(&Bs[row * BK + c * 8]);  \
      }                                                                   \
      _Pragma("unroll")                                                   \
      for (int fm = 0; fm < 4; ++fm)                                      \
        _Pragma("unroll")                                                 \
        for (int fn = 0; fn < 4; ++fn)                                    \
          acc[fm][fn] = __builtin_amdgcn_mfma_f32_16x16x32_f16(           \
              av[fm], bv[fn], acc[fm][fn], 0, 0, 0);                      \
    }                                                                     \
  }

  // ---- prologue: tile 0 (A regs oldest, then B DMA; cvt waits only A) ----
  ISSUE_A(0);
  STAGE_B(0);
  WRITE_A();
  if (nt == 0) NYQ();
  __syncthreads();  // B DMA drained; A ds_writes visible

  // ---- K loop: A(t+1) regs fly under COMPUTE(t); B(t+1) DMA after WAR ----
  for (int t = 0; t < KT; ++t) {
    if (t + 1 < KT) {
      ISSUE_A(t + 1);
      __builtin_amdgcn_sched_barrier(0);  // pin loads above the MFMA cluster
    }
    COMPUTE();
    if (t + 1 < KT) {
      __syncthreads();   // WAR: all As/Bs reads of tile t retired block-wide
      STAGE_B(t + 1);    // DMA into Bs (safe after WAR)
      WRITE_A();         // cvt+ds_write tile t+1 (A loads landed under COMPUTE)
      if (nt == 0) NYQ();
      __syncthreads();   // RAW: writes visible + B DMA drained
    }
  }

  // ---- epilogue (r9 verbatim): C/D col=lane&15, row=(lane>>4)*4+reg ----
#pragma unroll
  for (int fm = 0; fm < 4; ++fm) {
#pragma unroll
    for (int rr = 0; rr < 4; ++rr) {
      int row = m0 + wm + fm * 16 + lg * 4 + rr;
      size_t base = (size_t)row * NCOLS;
#pragma unroll
      for (int fn = 0; fn < 4; ++fn)
        out[base + n0 + wn + fn * 16 + lr] = acc[fm][fn][rr];
    }
  }

  // ---- Nyquist bin: col 512 = sum_n (-1)^n x[n], col 513 = 0 ----
  if (nt == 0) {
    float tot = nyq + __shfl_xor(nyq, 1);
    if ((tid & 1) == 0) {
      size_t base = (size_t)(m0 + arow) * NCOLS;
      out[base + 512] = tot;
      out[base + 513] = 0.0f;
    }
  }
#undef ISSUE_A
#undef WRITE_A
#undef NYQ
#undef STAGE_B
#undef COMPUTE
}

extern "C" void kernel_launch(void* const* d_in, const int* in_sizes, int n_in,
                              void* d_out, int out_size, void* d_ws, size_t ws_size,
                              hipStream_t stream) {
  const float* x  = (const float*)d_in[0];
  const float* rk = (const float*)d_in[1];
  const float* ik = (const float*)d_in[2];
  float* out = (float*)d_out;
  _Float16* wb = (_Float16*)d_ws;  // 512*512*2 B = 512 KB scratch

  prep_w<<<dim3(NPAD), dim3(KDIM), 0, stream>>>(rk, ik, wb);

  dim3 grid(NWG);
  dft_gemm<<<grid, dim3(256), 0, stream>>>(x, wb, out);
}